// Round 1
// baseline (577.593 us; speedup 1.0000x reference)
//
#include <hip/hip_runtime.h>
#include <math.h>

#define TT 8
#define NTOK 12288
#define DD 256
#define NNODE 8192
#define NNODES 32768
#define CLEN 16
#define CDIM 64
#define CHUNK 2048
#define H1 128

__device__ __forceinline__ float gelu_exact(float v) {
    return 0.5f * v * (1.0f + erff(v * 0.70710678118654752f));
}

// ---- Kernel 1: LN(x) rows + GEMM (xn @ w1, K=256 -> 128) + atomic scatter into a1 ----
// grid (128 rowblocks, 8 t), block 256. Each block: 64 rows x 128 cols.
__global__ __launch_bounds__(256) void k_ln_gemm_scatter(
    const float* __restrict__ x, const int* __restrict__ indices,
    const float* __restrict__ ln1_g, const float* __restrict__ ln1_b,
    const float* __restrict__ w1, float* __restrict__ a1)
{
    const int t = blockIdx.y;
    const int rowBase = blockIdx.x * 64;
    const int tid = threadIdx.x;

    __shared__ float As[64][36];     // normalized A k-tile, [row][k] (+pad)
    __shared__ float Bs[32][128];    // w1 k-tile
    __shared__ float red[64][4][2];
    __shared__ float mS[64], rS[64];

    const float* xblk = x + ((size_t)t * NTOK + rowBase) * DD;

    // pass 1: LN stats per row (4 threads/row)
    {
        const int row = tid >> 2, q = tid & 3;
        const float* xr = xblk + (size_t)row * DD;
        float s = 0.f, ss = 0.f;
        #pragma unroll
        for (int u = 0; u < 16; ++u) {
            const float4 v = *(const float4*)(xr + (u * 4 + q) * 4);
            s  += v.x + v.y + v.z + v.w;
            ss += v.x*v.x + v.y*v.y + v.z*v.z + v.w*v.w;
        }
        red[row][q][0] = s;
        red[row][q][1] = ss;
    }
    __syncthreads();
    if (tid < 64) {
        const float s  = red[tid][0][0] + red[tid][1][0] + red[tid][2][0] + red[tid][3][0];
        const float ss = red[tid][0][1] + red[tid][1][1] + red[tid][2][1] + red[tid][3][1];
        const float m = s * (1.0f / 256.0f);
        const float var = ss * (1.0f / 256.0f) - m * m;
        mS[tid] = m;
        rS[tid] = rsqrtf(var + 1e-5f);
    }
    __syncthreads();

    const int ty = tid >> 4;   // rows ty*4 .. ty*4+3
    const int tx = tid & 15;   // cols tx*8 .. tx*8+7
    float acc[4][8];
    #pragma unroll
    for (int j = 0; j < 4; ++j)
        #pragma unroll
        for (int jj = 0; jj < 8; ++jj) acc[j][jj] = 0.f;

    for (int kt = 0; kt < 8; ++kt) {
        // stage normalized A tile (64x32)
        #pragma unroll
        for (int u = 0; u < 2; ++u) {
            const int f = tid + u * 256;
            const int row = f >> 3, c4 = f & 7;
            const int k0 = kt * 32 + c4 * 4;
            float4 v = *(const float4*)(xblk + (size_t)row * DD + k0);
            const float4 g = *(const float4*)(ln1_g + k0);
            const float4 b = *(const float4*)(ln1_b + k0);
            const float m = mS[row], r = rS[row];
            v.x = (v.x - m) * r * g.x + b.x;
            v.y = (v.y - m) * r * g.y + b.y;
            v.z = (v.z - m) * r * g.z + b.z;
            v.w = (v.w - m) * r * g.w + b.w;
            *(float4*)&As[row][c4 * 4] = v;
        }
        // stage B tile (32x128)
        #pragma unroll
        for (int u = 0; u < 4; ++u) {
            const int f = tid + u * 256;
            const int row = f >> 5, c4 = f & 31;
            *(float4*)&Bs[row][c4 * 4] =
                *(const float4*)(w1 + (size_t)(kt * 32 + row) * H1 + c4 * 4);
        }
        __syncthreads();
        #pragma unroll
        for (int k = 0; k < 32; ++k) {
            const float a0 = As[ty*4+0][k];
            const float a1r = As[ty*4+1][k];
            const float a2 = As[ty*4+2][k];
            const float a3 = As[ty*4+3][k];
            const float4 b0 = *(const float4*)&Bs[k][tx*8];
            const float4 b4 = *(const float4*)&Bs[k][tx*8+4];
#define ACC_ROW(J, AJ) \
            acc[J][0] += AJ*b0.x; acc[J][1] += AJ*b0.y; acc[J][2] += AJ*b0.z; acc[J][3] += AJ*b0.w; \
            acc[J][4] += AJ*b4.x; acc[J][5] += AJ*b4.y; acc[J][6] += AJ*b4.z; acc[J][7] += AJ*b4.w;
            ACC_ROW(0, a0) ACC_ROW(1, a1r) ACC_ROW(2, a2) ACC_ROW(3, a3)
#undef ACC_ROW
        }
        __syncthreads();
    }

    // scatter-add: a1[t, idx[row], :] += y[row, :]
    const int* idxp = indices + (size_t)t * NNODE + rowBase;
    #pragma unroll
    for (int j = 0; j < 4; ++j) {
        const int node = idxp[ty * 4 + j];
        float* dst = a1 + ((size_t)t * NNODES + node) * H1 + tx * 8;
        #pragma unroll
        for (int jj = 0; jj < 8; ++jj) atomicAdd(dst + jj, acc[j][jj]);
    }
}

// ---- Kernel 2: sbuf[t,l,k] = sum over 2048 chunk rows of gelu(a1 + b1) ----
// grid (sub 8, l 16, t 8), block 256 (2 row-phases x 128 cols)
__global__ __launch_bounds__(256) void k_gelu_colsum(
    const float* __restrict__ a1, const float* __restrict__ b1,
    float* __restrict__ sbuf)
{
    const int tid = threadIdx.x;
    const int c = tid & 127, h = tid >> 7;
    const int sub = blockIdx.x, l = blockIdx.y, t = blockIdx.z;
    const float bb = b1[c];
    const float* base = a1 + ((size_t)t * NNODES + l * CHUNK + sub * 256 + h) * H1 + c;
    float acc = 0.f;
    #pragma unroll 4
    for (int r = 0; r < 128; ++r)
        acc += gelu_exact(base[(size_t)r * (2 * H1)] + bb);
    __shared__ float red[256];
    red[tid] = acc;
    __syncthreads();
    if (tid < 128) atomicAdd(&sbuf[(t * CLEN + l) * H1 + c], red[tid] + red[tid + 128]);
}

// ---- Kernel 3: comp = sbuf @ w2 + 2048*b2 ; lnf ; lnd ; decoder MLP -> decRow[t,16,256] ----
// grid 8 (per t), block 256
__global__ __launch_bounds__(256) void k_decode(
    const float* __restrict__ sbuf, const float* __restrict__ w2,
    const float* __restrict__ b2,
    const float* __restrict__ lnf_g, const float* __restrict__ lnf_b,
    const float* __restrict__ lnd_g, const float* __restrict__ lnd_b,
    const float* __restrict__ dw1, const float* __restrict__ db1,
    const float* __restrict__ dw2, const float* __restrict__ db2,
    float* __restrict__ decRow)
{
    const int t = blockIdx.x, tid = threadIdx.x;
    __shared__ float comp[CLEN * CDIM];   // 1024
    __shared__ float2 red2[256];
    __shared__ float vv[CLEN][CDIM];
    __shared__ float hh[CLEN][H1];
    __shared__ float mvS[2];
    __shared__ float m2S[CLEN], r2S[CLEN];

    // 1) comp = sbuf[t] @ w2 + CHUNK*b2
    #pragma unroll
    for (int u = 0; u < 4; ++u) {
        const int j = tid + u * 256;
        const int l = j >> 6, cc = j & 63;
        const float* sp = sbuf + (t * CLEN + l) * H1;
        float a = (float)CHUNK * b2[cc];
        for (int k = 0; k < H1; ++k) a += sp[k] * w2[k * CDIM + cc];
        comp[j] = a;
    }
    __syncthreads();
    // 2) lnf over the 1024 values
    {
        float s = 0.f, ss = 0.f;
        #pragma unroll
        for (int u = 0; u < 4; ++u) { const float v = comp[tid + u * 256]; s += v; ss += v * v; }
        red2[tid] = make_float2(s, ss);
        __syncthreads();
        for (int st = 128; st > 0; st >>= 1) {
            if (tid < st) {
                red2[tid].x += red2[tid + st].x;
                red2[tid].y += red2[tid + st].y;
            }
            __syncthreads();
        }
        if (tid == 0) {
            const float m = red2[0].x * (1.0f / 1024.0f);
            const float var = red2[0].y * (1.0f / 1024.0f) - m * m;
            mvS[0] = m; mvS[1] = rsqrtf(var + 1e-5f);
        }
        __syncthreads();
        const float m = mvS[0], r = mvS[1];
        #pragma unroll
        for (int u = 0; u < 4; ++u) {
            const int j = tid + u * 256;
            comp[j] = (comp[j] - m) * r * lnf_g[j] + lnf_b[j];
        }
    }
    __syncthreads();
    // 3) lnd per 64-wide row
    {
        const int l = tid >> 4, q = tid & 15;
        float s = 0.f, ss = 0.f;
        #pragma unroll
        for (int e = 0; e < 4; ++e) {
            const float v = comp[l * CDIM + q * 4 + e];
            s += v; ss += v * v;
        }
        red2[tid] = make_float2(s, ss);
        __syncthreads();
        if (tid < CLEN) {
            float sa = 0.f, sb = 0.f;
            for (int k = 0; k < 16; ++k) { sa += red2[tid * 16 + k].x; sb += red2[tid * 16 + k].y; }
            const float m = sa * (1.0f / 64.0f);
            const float var = sb * (1.0f / 64.0f) - m * m;
            m2S[tid] = m; r2S[tid] = rsqrtf(var + 1e-5f);
        }
        __syncthreads();
        #pragma unroll
        for (int u = 0; u < 4; ++u) {
            const int j = tid + u * 256;
            const int l2 = j >> 6, cc = j & 63;
            vv[l2][cc] = (comp[j] - m2S[l2]) * r2S[l2] * lnd_g[cc] + lnd_b[cc];
        }
    }
    __syncthreads();
    // 4) hh = gelu(vv @ dw1 + db1)
    #pragma unroll
    for (int u = 0; u < 8; ++u) {
        const int j = tid + u * 256;   // 0..2047
        const int l = j >> 7, cc = j & 127;
        float a = db1[cc];
        for (int k = 0; k < CDIM; ++k) a += vv[l][k] * dw1[k * H1 + cc];
        hh[l][cc] = gelu_exact(a);
    }
    __syncthreads();
    // 5) decRow = hh @ dw2 + db2
    #pragma unroll
    for (int u = 0; u < 16; ++u) {
        const int j = tid + u * 256;   // 0..4095
        const int l = j >> 8, cc = j & 255;
        float a = db2[cc];
        for (int k = 0; k < H1; ++k) a += hh[l][k] * dw2[k * DD + cc];
        decRow[(t * CLEN + l) * DD + cc] = a;
    }
}

// ---- Kernel 4: out[t,i,:] = decRow[t, idx[t,i]>>11, :] for i<8192 else 0 ----
// block 256 = 4 rows x 64 float4
__global__ __launch_bounds__(256) void k_gather(
    const int* __restrict__ indices, const float* __restrict__ decRow,
    float* __restrict__ out)
{
    const int tid = threadIdx.x;
    const int r = blockIdx.x * 4 + (tid >> 6);   // 0..98303
    const int c4 = tid & 63;
    const int t = r / NTOK;
    const int i = r - t * NTOK;
    float4 v = make_float4(0.f, 0.f, 0.f, 0.f);
    if (i < NNODE) {
        const int node = indices[t * NNODE + i];
        const int l = node >> 11;   // node / 2048
        v = *(const float4*)(decRow + (t * CLEN + l) * DD + c4 * 4);
    }
    *(float4*)(out + (size_t)r * DD + c4 * 4) = v;
}

extern "C" void kernel_launch(void* const* d_in, const int* in_sizes, int n_in,
                              void* d_out, int out_size, void* d_ws, size_t ws_size,
                              hipStream_t stream)
{
    const float* x     = (const float*)d_in[0];
    const int*   indices = (const int*)d_in[1];
    const float* ln1_g = (const float*)d_in[2];
    const float* ln1_b = (const float*)d_in[3];
    const float* w1    = (const float*)d_in[4];
    const float* b1    = (const float*)d_in[5];
    const float* w2    = (const float*)d_in[6];
    const float* b2    = (const float*)d_in[7];
    const float* lnf_g = (const float*)d_in[8];
    const float* lnf_b = (const float*)d_in[9];
    const float* lnd_g = (const float*)d_in[10];
    const float* lnd_b = (const float*)d_in[11];
    const float* dw1   = (const float*)d_in[12];
    const float* db1   = (const float*)d_in[13];
    const float* dw2   = (const float*)d_in[14];
    const float* db2   = (const float*)d_in[15];
    float* out = (float*)d_out;

    char* ws = (char*)d_ws;
    float* sbuf   = (float*)ws;                              // 8*16*128*4  = 64 KiB
    float* a1     = (float*)(ws + 65536);                    // 8*32768*128*4 = 128 MiB
    float* decRow = (float*)(ws + 65536 + 134217728);        // 8*16*256*4 = 128 KiB

    // zero the accumulation buffers (sbuf + a1, contiguous)
    hipMemsetAsync(d_ws, 0, 65536 + 134217728, stream);

    k_ln_gemm_scatter<<<dim3(128, 8), 256, 0, stream>>>(x, indices, ln1_g, ln1_b, w1, a1);
    k_gelu_colsum<<<dim3(8, 16, 8), 256, 0, stream>>>(a1, b1, sbuf);
    k_decode<<<8, 256, 0, stream>>>(sbuf, w2, b2, lnf_g, lnf_b, lnd_g, lnd_b,
                                    dw1, db1, dw2, db2, decRow);
    k_gather<<<24576, 256, 0, stream>>>(indices, decRow, out);
}